// Round 3
// baseline (97.927 us; speedup 1.0000x reference)
//
#include <hip/hip_runtime.h>

// VQ2D nearest-code assignment, N=16.7M points, K=4 codes, 2-D.
// Outputs concatenated flat (float32): [q_grad N*2][idx N][q N*2].
// q_grad forward value == q (STE), idx written as float.
// Pure streaming: ~470 MB traffic -> HBM-bound. R2: 4x unroll for MLP +
// nontemporal loads/stores; vq1 returns struct (vector elems can't bind
// to non-const refs).

typedef float f32x4 __attribute__((ext_vector_type(4)));
typedef float f32x2 __attribute__((ext_vector_type(2)));

struct VQR { float qx, qy, fi; };

__device__ __forceinline__ VQR vq1(float zx, float zy,
                                   float cx0, float cy0, float cx1, float cy1,
                                   float cx2, float cy2, float cx3, float cy3)
{
    float dx = zx - cx0, dy = zy - cy0;
    float best = dx * dx + dy * dy;
    VQR r; r.qx = cx0; r.qy = cy0; r.fi = 0.0f;

    dx = zx - cx1; dy = zy - cy1;
    float d = dx * dx + dy * dy;
    if (d < best) { best = d; r.qx = cx1; r.qy = cy1; r.fi = 1.0f; }

    dx = zx - cx2; dy = zy - cy2;
    d = dx * dx + dy * dy;
    if (d < best) { best = d; r.qx = cx2; r.qy = cy2; r.fi = 2.0f; }

    dx = zx - cx3; dy = zy - cy3;
    d = dx * dx + dy * dy;
    if (d < best) { best = d; r.qx = cx3; r.qy = cy3; r.fi = 3.0f; }

    return r;
}

__global__ __launch_bounds__(256) void VQ2D_26938034881022_kernel(
    const f32x4* __restrict__ z4,   // [npairs] (2 points per f32x4)
    const float* __restrict__ cb,   // [4,2]
    float* __restrict__ out,        // [5N]
    long long npairs,
    long long N)
{
    float cx0 = cb[0], cy0 = cb[1];
    float cx1 = cb[2], cy1 = cb[3];
    float cx2 = cb[4], cy2 = cb[5];
    float cx3 = cb[6], cy3 = cb[7];

    f32x4* __restrict__ qg4 = reinterpret_cast<f32x4*>(out);            // q_grad
    f32x2* __restrict__ id2 = reinterpret_cast<f32x2*>(out + 2 * N);    // idx
    f32x4* __restrict__ q4  = reinterpret_cast<f32x4*>(out + 3 * N);    // q

    const long long T = (long long)gridDim.x * blockDim.x;
    long long t = (long long)blockIdx.x * blockDim.x + threadIdx.x;

    // Fast path: 4 pairs per iteration, stride-T batched -> 4 outstanding
    // loads per lane, all streams unit-stride within each instruction.
    for (; t + 3 * T < npairs; t += 4 * T) {
        f32x4 z0 = __builtin_nontemporal_load(z4 + t);
        f32x4 z1 = __builtin_nontemporal_load(z4 + t + T);
        f32x4 z2 = __builtin_nontemporal_load(z4 + t + 2 * T);
        f32x4 z3 = __builtin_nontemporal_load(z4 + t + 3 * T);

        VQR a0 = vq1(z0.x, z0.y, cx0,cy0,cx1,cy1,cx2,cy2,cx3,cy3);
        VQR b0 = vq1(z0.z, z0.w, cx0,cy0,cx1,cy1,cx2,cy2,cx3,cy3);
        VQR a1 = vq1(z1.x, z1.y, cx0,cy0,cx1,cy1,cx2,cy2,cx3,cy3);
        VQR b1 = vq1(z1.z, z1.w, cx0,cy0,cx1,cy1,cx2,cy2,cx3,cy3);
        VQR a2 = vq1(z2.x, z2.y, cx0,cy0,cx1,cy1,cx2,cy2,cx3,cy3);
        VQR b2 = vq1(z2.z, z2.w, cx0,cy0,cx1,cy1,cx2,cy2,cx3,cy3);
        VQR a3 = vq1(z3.x, z3.y, cx0,cy0,cx1,cy1,cx2,cy2,cx3,cy3);
        VQR b3 = vq1(z3.z, z3.w, cx0,cy0,cx1,cy1,cx2,cy2,cx3,cy3);

        f32x4 q0 = { a0.qx, a0.qy, b0.qx, b0.qy };
        f32x4 q1 = { a1.qx, a1.qy, b1.qx, b1.qy };
        f32x4 q2 = { a2.qx, a2.qy, b2.qx, b2.qy };
        f32x4 q3 = { a3.qx, a3.qy, b3.qx, b3.qy };
        f32x2 i0 = { a0.fi, b0.fi };
        f32x2 i1 = { a1.fi, b1.fi };
        f32x2 i2 = { a2.fi, b2.fi };
        f32x2 i3 = { a3.fi, b3.fi };

        __builtin_nontemporal_store(q0, qg4 + t);
        __builtin_nontemporal_store(q1, qg4 + t + T);
        __builtin_nontemporal_store(q2, qg4 + t + 2 * T);
        __builtin_nontemporal_store(q3, qg4 + t + 3 * T);
        __builtin_nontemporal_store(q0, q4 + t);
        __builtin_nontemporal_store(q1, q4 + t + T);
        __builtin_nontemporal_store(q2, q4 + t + 2 * T);
        __builtin_nontemporal_store(q3, q4 + t + 3 * T);
        __builtin_nontemporal_store(i0, id2 + t);
        __builtin_nontemporal_store(i1, id2 + t + T);
        __builtin_nontemporal_store(i2, id2 + t + 2 * T);
        __builtin_nontemporal_store(i3, id2 + t + 3 * T);
    }

    // Tail (not taken for N=16,777,216 with grid 2048x256).
    for (; t < npairs; t += T) {
        f32x4 zz = __builtin_nontemporal_load(z4 + t);
        VQR a = vq1(zz.x, zz.y, cx0,cy0,cx1,cy1,cx2,cy2,cx3,cy3);
        VQR b = vq1(zz.z, zz.w, cx0,cy0,cx1,cy1,cx2,cy2,cx3,cy3);
        f32x4 q = { a.qx, a.qy, b.qx, b.qy };
        f32x2 fi = { a.fi, b.fi };
        __builtin_nontemporal_store(q, qg4 + t);
        __builtin_nontemporal_store(q, q4 + t);
        __builtin_nontemporal_store(fi, id2 + t);
    }
}

extern "C" void kernel_launch(void* const* d_in, const int* in_sizes, int n_in,
                              void* d_out, int out_size, void* d_ws, size_t ws_size,
                              hipStream_t stream) {
    const f32x4* z4 = (const f32x4*)d_in[0];
    const float* cb = (const float*)d_in[1];
    float* out = (float*)d_out;

    long long N = (long long)in_sizes[0] / 2;  // in_sizes[0] = N*2
    long long npairs = N / 2;                  // N is even

    int block = 256;
    long long want = (npairs + block - 1) / block;
    int grid = (int)(want < 2048 ? want : 2048);

    VQ2D_26938034881022_kernel<<<grid, block, 0, stream>>>(z4, cb, out, npairs, N);
}

// Round 4
// 77.694 us; speedup vs baseline: 1.2604x; 1.2604x over previous
//
#include <hip/hip_runtime.h>

// VQ2D nearest-code assignment, N=16.7M points, K=4 codes, 2-D.
// Outputs concatenated flat (float32): [q_grad N*2][idx N][q N*2].
// q_grad forward value == q (STE), idx written as float.
// ~470 MB traffic -> HBM-bound.
// R3: R0 structure + nontemporal STORES only (keep z L3-resident across
// graph replays; NT loads would forbid that retention). Plain loads.

typedef float f32x4 __attribute__((ext_vector_type(4)));
typedef float f32x2 __attribute__((ext_vector_type(2)));

struct VQR { float qx, qy, fi; };

__device__ __forceinline__ VQR vq1(float zx, float zy,
                                   float cx0, float cy0, float cx1, float cy1,
                                   float cx2, float cy2, float cx3, float cy3)
{
    float dx = zx - cx0, dy = zy - cy0;
    float best = dx * dx + dy * dy;
    VQR r; r.qx = cx0; r.qy = cy0; r.fi = 0.0f;

    dx = zx - cx1; dy = zy - cy1;
    float d = dx * dx + dy * dy;
    if (d < best) { best = d; r.qx = cx1; r.qy = cy1; r.fi = 1.0f; }

    dx = zx - cx2; dy = zy - cy2;
    d = dx * dx + dy * dy;
    if (d < best) { best = d; r.qx = cx2; r.qy = cy2; r.fi = 2.0f; }

    dx = zx - cx3; dy = zy - cy3;
    d = dx * dx + dy * dy;
    if (d < best) { best = d; r.qx = cx3; r.qy = cy3; r.fi = 3.0f; }

    return r;
}

__global__ __launch_bounds__(256) void VQ2D_26938034881022_kernel(
    const f32x4* __restrict__ z4,   // [npairs] (2 points per f32x4)
    const float* __restrict__ cb,   // [4,2]
    float* __restrict__ out,        // [5N]
    int npairs,
    long long N)
{
    float cx0 = cb[0], cy0 = cb[1];
    float cx1 = cb[2], cy1 = cb[3];
    float cx2 = cb[4], cy2 = cb[5];
    float cx3 = cb[6], cy3 = cb[7];

    f32x4* __restrict__ qg4 = reinterpret_cast<f32x4*>(out);            // q_grad
    f32x2* __restrict__ id2 = reinterpret_cast<f32x2*>(out + 2 * N);    // idx
    f32x4* __restrict__ q4  = reinterpret_cast<f32x4*>(out + 3 * N);    // q

    const int T = (int)(gridDim.x * blockDim.x);
    for (int t = (int)(blockIdx.x * blockDim.x + threadIdx.x);
         t < npairs; t += T) {
        f32x4 zz = z4[t];  // plain load: allow L2/L3 to serve + retain z

        VQR a = vq1(zz.x, zz.y, cx0,cy0,cx1,cy1,cx2,cy2,cx3,cy3);
        VQR b = vq1(zz.z, zz.w, cx0,cy0,cx1,cy1,cx2,cy2,cx3,cy3);

        f32x4 q  = { a.qx, a.qy, b.qx, b.qy };
        f32x2 fi = { a.fi, b.fi };

        __builtin_nontemporal_store(q,  qg4 + t);
        __builtin_nontemporal_store(q,  q4  + t);
        __builtin_nontemporal_store(fi, id2 + t);
    }
}

extern "C" void kernel_launch(void* const* d_in, const int* in_sizes, int n_in,
                              void* d_out, int out_size, void* d_ws, size_t ws_size,
                              hipStream_t stream) {
    const f32x4* z4 = (const f32x4*)d_in[0];
    const float* cb = (const float*)d_in[1];
    float* out = (float*)d_out;

    long long N = (long long)in_sizes[0] / 2;  // in_sizes[0] = N*2
    int npairs = (int)(N / 2);                 // 8.4M, fits int32

    int block = 256;
    long long want = ((long long)npairs + block - 1) / block;
    int grid = (int)(want < 2048 ? want : 2048);

    VQ2D_26938034881022_kernel<<<grid, block, 0, stream>>>(z4, cb, out, npairs, N);
}

// Round 5
// 74.442 us; speedup vs baseline: 1.3155x; 1.0437x over previous
//
#include <hip/hip_runtime.h>

// VQ2D nearest-code assignment, N=16.7M points, K=4 codes, 2-D.
// Outputs concatenated flat (float32): [q_grad N*2][idx N][q N*2].
// q_grad forward value == q (STE), idx written as float.
// ~470 MB traffic -> HBM-bound.
// R4: R3 (plain loads + NT stores) + unroll x2 stride-T batched.
// Isolates the unroll lever from R2's NT-load regression.

typedef float f32x4 __attribute__((ext_vector_type(4)));
typedef float f32x2 __attribute__((ext_vector_type(2)));

struct VQR { float qx, qy, fi; };

__device__ __forceinline__ VQR vq1(float zx, float zy,
                                   float cx0, float cy0, float cx1, float cy1,
                                   float cx2, float cy2, float cx3, float cy3)
{
    float dx = zx - cx0, dy = zy - cy0;
    float best = dx * dx + dy * dy;
    VQR r; r.qx = cx0; r.qy = cy0; r.fi = 0.0f;

    dx = zx - cx1; dy = zy - cy1;
    float d = dx * dx + dy * dy;
    if (d < best) { best = d; r.qx = cx1; r.qy = cy1; r.fi = 1.0f; }

    dx = zx - cx2; dy = zy - cy2;
    d = dx * dx + dy * dy;
    if (d < best) { best = d; r.qx = cx2; r.qy = cy2; r.fi = 2.0f; }

    dx = zx - cx3; dy = zy - cy3;
    d = dx * dx + dy * dy;
    if (d < best) { best = d; r.qx = cx3; r.qy = cy3; r.fi = 3.0f; }

    return r;
}

__global__ __launch_bounds__(256) void VQ2D_26938034881022_kernel(
    const f32x4* __restrict__ z4,   // [npairs] (2 points per f32x4)
    const float* __restrict__ cb,   // [4,2]
    float* __restrict__ out,        // [5N]
    int npairs,
    long long N)
{
    float cx0 = cb[0], cy0 = cb[1];
    float cx1 = cb[2], cy1 = cb[3];
    float cx2 = cb[4], cy2 = cb[5];
    float cx3 = cb[6], cy3 = cb[7];

    f32x4* __restrict__ qg4 = reinterpret_cast<f32x4*>(out);            // q_grad
    f32x2* __restrict__ id2 = reinterpret_cast<f32x2*>(out + 2 * N);    // idx
    f32x4* __restrict__ q4  = reinterpret_cast<f32x4*>(out + 3 * N);    // q

    const int T = (int)(gridDim.x * blockDim.x);
    int t = (int)(blockIdx.x * blockDim.x + threadIdx.x);

    // 2 pairs per iteration, stride-T batched: 2 outstanding plain loads,
    // then 6 NT stores.
    for (; t + T < npairs; t += 2 * T) {
        f32x4 zz0 = z4[t];
        f32x4 zz1 = z4[t + T];

        VQR a0 = vq1(zz0.x, zz0.y, cx0,cy0,cx1,cy1,cx2,cy2,cx3,cy3);
        VQR b0 = vq1(zz0.z, zz0.w, cx0,cy0,cx1,cy1,cx2,cy2,cx3,cy3);
        VQR a1 = vq1(zz1.x, zz1.y, cx0,cy0,cx1,cy1,cx2,cy2,cx3,cy3);
        VQR b1 = vq1(zz1.z, zz1.w, cx0,cy0,cx1,cy1,cx2,cy2,cx3,cy3);

        f32x4 q0 = { a0.qx, a0.qy, b0.qx, b0.qy };
        f32x4 q1 = { a1.qx, a1.qy, b1.qx, b1.qy };
        f32x2 i0 = { a0.fi, b0.fi };
        f32x2 i1 = { a1.fi, b1.fi };

        __builtin_nontemporal_store(q0, qg4 + t);
        __builtin_nontemporal_store(q1, qg4 + t + T);
        __builtin_nontemporal_store(q0, q4  + t);
        __builtin_nontemporal_store(q1, q4  + t + T);
        __builtin_nontemporal_store(i0, id2 + t);
        __builtin_nontemporal_store(i1, id2 + t + T);
    }

    // Tail (not taken for N=16,777,216 with grid 2048x256).
    for (; t < npairs; t += T) {
        f32x4 zz = z4[t];
        VQR a = vq1(zz.x, zz.y, cx0,cy0,cx1,cy1,cx2,cy2,cx3,cy3);
        VQR b = vq1(zz.z, zz.w, cx0,cy0,cx1,cy1,cx2,cy2,cx3,cy3);
        f32x4 q  = { a.qx, a.qy, b.qx, b.qy };
        f32x2 fi = { a.fi, b.fi };
        __builtin_nontemporal_store(q,  qg4 + t);
        __builtin_nontemporal_store(q,  q4  + t);
        __builtin_nontemporal_store(fi, id2 + t);
    }
}

extern "C" void kernel_launch(void* const* d_in, const int* in_sizes, int n_in,
                              void* d_out, int out_size, void* d_ws, size_t ws_size,
                              hipStream_t stream) {
    const f32x4* z4 = (const f32x4*)d_in[0];
    const float* cb = (const float*)d_in[1];
    float* out = (float*)d_out;

    long long N = (long long)in_sizes[0] / 2;  // in_sizes[0] = N*2
    int npairs = (int)(N / 2);                 // 8.4M, fits int32

    int block = 256;
    long long want = ((long long)npairs + block - 1) / block;
    int grid = (int)(want < 2048 ? want : 2048);

    VQ2D_26938034881022_kernel<<<grid, block, 0, stream>>>(z4, cb, out, npairs, N);
}